// Round 1
// baseline (368.937 us; speedup 1.0000x reference)
//
#include <hip/hip_runtime.h>
#include <math.h>

#define B_ 16
#define N_ 4096
#define D_ 512
#define M_ 64
#define MD 32768   // M_*D_

typedef __attribute__((ext_vector_type(4))) float f32x4;
typedef __attribute__((ext_vector_type(8))) short short8;

// ---- workspace layout (float offsets) ----
#define OFF_PSUM   0          // [16][16][512] pooling sum partials
#define OFF_PMAXP  131072     // [16][16][512] pooling max partials
#define OFF_CTXC   262144     // [256][16][4]  ctx swizzled: (k4, b, j) -> ctx[b][4*k4+j]
#define OFF_P      278528     // [16][32768]   prototypes, P[b][m*512+d]
#define OFF_CB     802816     // [16][64]      c' = (P . b_pre)/64
#define OFF_GMAX   803840     // [16][64]
#define OFF_GINV   804864     // [16][64]
#define OFF_TPMAX  805888     // [16][64][256] per-ntile max
#define OFF_TPSUM  1068032    // [16][64][256] per-ntile sumexp
#define OFF_QB     1330176    // bf16 [16][64][512] as ushort (262144 floats)
#define OFF_LOGITS 1592320    // [16][4096][64]
// total = 5786624 floats = 23.1 MB

__device__ __forceinline__ unsigned short f2bf(float f) {
    unsigned int u = __float_as_uint(f);
    u += 0x7fffu + ((u >> 16) & 1u);   // round-to-nearest-even
    return (unsigned short)(u >> 16);
}

// ---- K1: pooling partials. grid 256 (b*16+nc), block 256 ----
__global__ __launch_bounds__(256) void k_pool(const float* __restrict__ X, float* __restrict__ ws) {
    int b = blockIdx.x >> 4, nc = blockIdx.x & 15, t = threadIdx.x;
    const float2* X2 = (const float2*)X;
    float2 s = make_float2(0.f, 0.f);
    float2 mx = make_float2(-INFINITY, -INFINITY);
    int base = (b * N_ + nc * 256) * 256 + t;   // float2 units; row stride 256
    for (int n = 0; n < 256; n++) {
        float2 v = X2[base + n * 256];
        s.x += v.x; s.y += v.y;
        mx.x = fmaxf(mx.x, v.x); mx.y = fmaxf(mx.y, v.y);
    }
    ((float2*)(ws + OFF_PSUM))[blockIdx.x * 256 + t] = s;
    ((float2*)(ws + OFF_PMAXP))[blockIdx.x * 256 + t] = mx;
}

// ---- K1b: finalize ctx into swizzled ctx_c. grid 64, block 256 ----
__global__ __launch_bounds__(256) void k_ctx(float* __restrict__ ws) {
    int idx = blockIdx.x * 256 + threadIdx.x;     // 0..16383 = k4*64 + b*4 + j
    int b = (idx >> 2) & 15, j = idx & 3, k4 = idx >> 6;
    int k = k4 * 4 + j;
    float v;
    if (k < 512) {
        float s = 0.f;
        for (int c = 0; c < 16; c++) s += ws[OFF_PSUM + (b * 16 + c) * 512 + k];
        v = s * (1.0f / 4096.0f);
    } else {
        int d = k - 512;
        float m = -INFINITY;
        for (int c = 0; c < 16; c++) m = fmaxf(m, ws[OFF_PMAXP + (b * 16 + c) * 512 + d]);
        v = m;
    }
    ws[OFF_CTXC + idx] = v;
}

// ---- K2: prototypes P[b][r] = base[r] + b_ctx[r] + ctx[b].W_ctx[r]. grid 2048, block 256 ----
__global__ __launch_bounds__(256) void k_protos(const float* __restrict__ Wc, const float* __restrict__ pb,
                                                const float* __restrict__ bc, float* __restrict__ ws) {
    int t = threadIdx.x;
    int gw = blockIdx.x * 4 + (t >> 6);   // global wave id, 0..8191
    int l = t & 63;
    int r = gw * 4 + (l >> 4);            // row of W_ctx (= flat m*512+d), 4 rows/wave
    int bb = l & 15;                      // batch
    const float4* W4 = (const float4*)Wc;
    const float4* C4 = (const float4*)(ws + OFF_CTXC);
    float acc = 0.f;
    int wbase = r * 256;
    for (int k4 = 0; k4 < 256; k4++) {
        float4 w = W4[wbase + k4];
        float4 c = C4[k4 * 16 + bb];
        acc += w.x * c.x + w.y * c.y + w.z * c.z + w.w * c.w;
    }
    ws[OFF_P + bb * MD + r] = acc + pb[r] + bc[r];
}

// ---- K3: Q'[b] = P[b] @ W_pre / 64 (bf16 out). grid 128 (b*8+mg), block 256 ----
__global__ __launch_bounds__(256) void k_q(const float* __restrict__ Wp, float* __restrict__ ws) {
    int b = blockIdx.x >> 3, m0 = (blockIdx.x & 7) * 8, t = threadIdx.x;
    float acc0[8], acc1[8];
#pragma unroll
    for (int i = 0; i < 8; i++) { acc0[i] = 0.f; acc1[i] = 0.f; }
    const float* Pb = ws + OFF_P + b * MD;
    for (int j = 0; j < 512; j++) {
        float w0 = Wp[j * 512 + t];
        float w1 = Wp[j * 512 + t + 256];
#pragma unroll
        for (int mm = 0; mm < 8; mm++) {
            float p = Pb[(m0 + mm) * 512 + j];   // uniform -> s_load
            acc0[mm] += p * w0;
            acc1[mm] += p * w1;
        }
    }
    unsigned short* Qb = (unsigned short*)(ws + OFF_QB);
#pragma unroll
    for (int mm = 0; mm < 8; mm++) {
        Qb[(b * 64 + m0 + mm) * 512 + t]       = f2bf(acc0[mm] * (1.0f / 64.0f));
        Qb[(b * 64 + m0 + mm) * 512 + t + 256] = f2bf(acc1[mm] * (1.0f / 64.0f));
    }
}

// ---- K3b: c'[b][m] = (P[b][m] . b_pre)/64. grid 4, block 256 ----
__global__ __launch_bounds__(256) void k_cb(const float* __restrict__ bpre, float* __restrict__ ws) {
    int tid = blockIdx.x * 256 + threadIdx.x;   // 0..1023 = b*64+m
    int b = tid >> 6, m = tid & 63;
    const float4* P4 = (const float4*)(ws + OFF_P + b * MD + m * 512);
    const float4* bp4 = (const float4*)bpre;
    float s = 0.f;
    for (int j = 0; j < 128; j++) {
        float4 p = P4[j]; float4 q = bp4[j];
        s += p.x * q.x + p.y * q.y + p.z * q.z + p.w * q.w;
    }
    ws[OFF_CB + tid] = s * (1.0f / 64.0f);
}

// ---- K4: logits = X.Q'^T + c' via bf16 MFMA + per-tile softmax partials. grid 1024, block 256 ----
__global__ __launch_bounds__(256) void k_logits(const float* __restrict__ X, float* __restrict__ ws) {
    int t = threadIdx.x;
    int W = blockIdx.x * 4 + (t >> 6);   // wave id 0..4095
    int b = W >> 8, nt = W & 255;        // batch, n-tile (16 rows)
    int l = t & 63, col = l & 15, kg = l >> 4;
    int nA = nt * 16 + col;              // A-fragment row
    const float4* X4 = (const float4*)X;
    const short8* Qb8 = (const short8*)(ws + OFF_QB);
    f32x4 acc[4];
#pragma unroll
    for (int mt = 0; mt < 4; mt++) acc[mt] = (f32x4){0.f, 0.f, 0.f, 0.f};

    int xbase4 = ((b * N_ + nA) * D_) >> 2;
    for (int kc = 0; kc < 16; kc++) {
        int k = kc * 32 + kg * 8;
        float4 xa = X4[xbase4 + (k >> 2)];
        float4 xb = X4[xbase4 + (k >> 2) + 1];
        short8 af;
        af[0] = (short)f2bf(xa.x); af[1] = (short)f2bf(xa.y);
        af[2] = (short)f2bf(xa.z); af[3] = (short)f2bf(xa.w);
        af[4] = (short)f2bf(xb.x); af[5] = (short)f2bf(xb.y);
        af[6] = (short)f2bf(xb.z); af[7] = (short)f2bf(xb.w);
#pragma unroll
        for (int mt = 0; mt < 4; mt++) {
            int m = mt * 16 + col;
            short8 bfr = Qb8[(b * 64 + m) * 64 + (k >> 3)];
            acc[mt] = __builtin_amdgcn_mfma_f32_16x16x32_bf16(af, bfr, acc[mt], 0, 0, 0);
        }
    }
    // epilogue: D[row=kg*4+reg][col] ; row is n-within-tile, col is m-within-mt
    const float* cb = ws + OFF_CB + b * 64;
    float* LG = ws + OFF_LOGITS + b * (N_ * 64) + nt * 16 * 64;
#pragma unroll
    for (int mt = 0; mt < 4; mt++) {
        int m = mt * 16 + col;
        float c = cb[m];
        float v0 = acc[mt][0] + c, v1 = acc[mt][1] + c;
        float v2 = acc[mt][2] + c, v3 = acc[mt][3] + c;
        int nr = kg * 4;
        LG[(nr + 0) * 64 + m] = v0;
        LG[(nr + 1) * 64 + m] = v1;
        LG[(nr + 2) * 64 + m] = v2;
        LG[(nr + 3) * 64 + m] = v3;
        float mx = fmaxf(fmaxf(v0, v1), fmaxf(v2, v3));
        mx = fmaxf(mx, __shfl_xor(mx, 16));
        mx = fmaxf(mx, __shfl_xor(mx, 32));
        float s = expf(v0 - mx) + expf(v1 - mx) + expf(v2 - mx) + expf(v3 - mx);
        s += __shfl_xor(s, 16);
        s += __shfl_xor(s, 32);
        if (kg == 0) {
            ws[OFF_TPMAX + (b * 64 + m) * 256 + nt] = mx;
            ws[OFF_TPSUM + (b * 64 + m) * 256 + nt] = s;
        }
    }
}

// ---- K5: combine partials -> gmax, 1/denom. grid 4, block 256 ----
__global__ __launch_bounds__(256) void k_combine(float* __restrict__ ws) {
    int tid = blockIdx.x * 256 + threadIdx.x;   // b*64+m
    const float* pm = ws + OFF_TPMAX + tid * 256;
    const float* pv = ws + OFF_TPSUM + tid * 256;
    float g = -INFINITY;
    for (int c = 0; c < 256; c++) g = fmaxf(g, pm[c]);
    float den = 0.f;
    for (int c = 0; c < 256; c++) den += pv[c] * expf(pm[c] - g);
    ws[OFF_GMAX + tid] = g;
    ws[OFF_GINV + tid] = 1.0f / den;
}

// ---- K6: out = exp(l - gmax) * ginv. grid 4096, block 256 ----
__global__ __launch_bounds__(256) void k_final(const float* __restrict__ ws, float* __restrict__ out) {
    int idx = blockIdx.x * 256 + threadIdx.x;   // float4 index
    int flat = idx * 4;
    int b = flat >> 18;                         // / (4096*64)
    int m0 = flat & 63;                         // multiple of 4
    float4 l4 = ((const float4*)(ws + OFF_LOGITS))[idx];
    int bm = b * 64 + m0;
    float4 g4 = *(const float4*)(ws + OFF_GMAX + bm);
    float4 i4 = *(const float4*)(ws + OFF_GINV + bm);
    float4 o;
    o.x = expf(l4.x - g4.x) * i4.x;
    o.y = expf(l4.y - g4.y) * i4.y;
    o.z = expf(l4.z - g4.z) * i4.z;
    o.w = expf(l4.w - g4.w) * i4.w;
    ((float4*)out)[idx] = o;
}

extern "C" void kernel_launch(void* const* d_in, const int* in_sizes, int n_in,
                              void* d_out, int out_size, void* d_ws, size_t ws_size,
                              hipStream_t stream) {
    const float* X  = (const float*)d_in[0];
    const float* pb = (const float*)d_in[1];
    const float* Wc = (const float*)d_in[2];
    const float* bc = (const float*)d_in[3];
    const float* Wp = (const float*)d_in[4];
    const float* bp = (const float*)d_in[5];
    float* ws  = (float*)d_ws;
    float* out = (float*)d_out;

    k_pool<<<256, 256, 0, stream>>>(X, ws);
    k_ctx<<<64, 256, 0, stream>>>(ws);
    k_protos<<<2048, 256, 0, stream>>>(Wc, pb, bc, ws);
    k_q<<<128, 256, 0, stream>>>(Wp, ws);
    k_cb<<<4, 256, 0, stream>>>(bp, ws);
    k_logits<<<1024, 256, 0, stream>>>(X, ws);
    k_combine<<<4, 256, 0, stream>>>(ws);
    k_final<<<4096, 256, 0, stream>>>(ws, out);
}

// Round 4
// 261.031 us; speedup vs baseline: 1.4134x; 1.4134x over previous
//
#include <hip/hip_runtime.h>
#include <math.h>

#define B_ 16
#define N_ 4096
#define D_ 512
#define M_ 64
#define MD 32768   // M_*D_

typedef __attribute__((ext_vector_type(4))) float f32x4;
typedef __attribute__((ext_vector_type(8))) short short8;

// ---- workspace layout (float offsets) ----
#define OFF_PSUM   0          // [16][16][512] pooling sum partials
#define OFF_PMAXP  131072     // [16][16][512] pooling max partials
#define OFF_CTXB   262144     // bf16 [16][1024] ctx (8192 floats worth)
#define OFF_P      270336     // fp32 P_t[32768][16]  (r-major, batch minor)
#define OFF_CB     794624     // [16][64]  c' = (P . b_pre)/64
#define OFF_GMAX   795648     // [16][64]
#define OFF_GINV   796672     // [16][64]
#define OFF_TPMAX  797696     // [1024][256] per-ntile max   (bm-major)
#define OFF_TPSUM  1059840    // [1024][256] per-ntile sumexp
#define OFF_QB     1321984    // bf16 [16][64][512] = 524288 bf16 = 262144 floats
#define OFF_LOGITS 1584128    // [16][4096][64]  (FIX: was 1453056 -> QB overflow race)
// total = 5778432 floats = 23.1 MB

__device__ __forceinline__ unsigned short f2bf(float f) {
    unsigned int u = __float_as_uint(f);
    u += 0x7fffu + ((u >> 16) & 1u);   // round-to-nearest-even
    return (unsigned short)(u >> 16);
}

// ---- K1: pooling partials. grid 256 (b*16+nc), block 256 ----
__global__ __launch_bounds__(256) void k_pool(const float* __restrict__ X, float* __restrict__ ws) {
    int b = blockIdx.x >> 4, nc = blockIdx.x & 15, t = threadIdx.x;
    const float2* X2 = (const float2*)X;
    float2 s = make_float2(0.f, 0.f);
    float2 mx = make_float2(-INFINITY, -INFINITY);
    int base = (b * N_ + nc * 256) * 256 + t;   // float2 units; row stride 256
    for (int n = 0; n < 256; n++) {
        float2 v = X2[base + n * 256];
        s.x += v.x; s.y += v.y;
        mx.x = fmaxf(mx.x, v.x); mx.y = fmaxf(mx.y, v.y);
    }
    ((float2*)(ws + OFF_PSUM))[blockIdx.x * 256 + t] = s;
    ((float2*)(ws + OFF_PMAXP))[blockIdx.x * 256 + t] = mx;
}

// ---- K1b: finalize ctx -> bf16 [b][1024]. grid 64, block 256 ----
__global__ __launch_bounds__(256) void k_ctx(float* __restrict__ ws) {
    int idx = blockIdx.x * 256 + threadIdx.x;     // 0..16383 = b*1024 + k
    int b = idx >> 10, k = idx & 1023;
    float v;
    if (k < 512) {
        float s = 0.f;
        for (int c = 0; c < 16; c++) s += ws[OFF_PSUM + (b * 16 + c) * 512 + k];
        v = s * (1.0f / 4096.0f);
    } else {
        int d = k - 512;
        float m = -INFINITY;
        for (int c = 0; c < 16; c++) m = fmaxf(m, ws[OFF_PMAXP + (b * 16 + c) * 512 + d]);
        v = m;
    }
    ((unsigned short*)(ws + OFF_CTXB))[idx] = f2bf(v);
}

// ---- K2: P via MFMA: C[32768,16] = W[32768,1024] @ ctx^T. grid 512, block 256 ----
__global__ __launch_bounds__(256) void k_protos(const float* __restrict__ Wc, const float* __restrict__ pb,
                                                const float* __restrict__ bc, float* __restrict__ ws) {
    int t = threadIdx.x;
    int wave = blockIdx.x * 4 + (t >> 6);   // 0..2047 tiles
    int l = t & 63;
    int r0 = wave * 16;
    int row = r0 + (l & 15);
    int kg = l >> 4;
    const float4* W4 = (const float4*)Wc;                  // row stride 256 float4
    const short8* CB8 = (const short8*)(ws + OFF_CTXB);    // [16][128] short8 units
    f32x4 acc = (f32x4){0.f, 0.f, 0.f, 0.f};
    int wb = row * 256 + kg * 2;            // float4 idx: k = kg*8
    int cbase = (l & 15) * 128 + kg;        // short8 idx: batch*128 + k/8
#pragma unroll 4
    for (int kc = 0; kc < 32; kc++) {
        float4 xa = W4[wb + kc * 8];
        float4 xb = W4[wb + kc * 8 + 1];
        short8 af;
        af[0] = (short)f2bf(xa.x); af[1] = (short)f2bf(xa.y);
        af[2] = (short)f2bf(xa.z); af[3] = (short)f2bf(xa.w);
        af[4] = (short)f2bf(xb.x); af[5] = (short)f2bf(xb.y);
        af[6] = (short)f2bf(xb.z); af[7] = (short)f2bf(xb.w);
        short8 bfr = CB8[cbase + kc * 4];
        acc = __builtin_amdgcn_mfma_f32_16x16x32_bf16(af, bfr, acc, 0, 0, 0);
    }
    int orow = r0 + kg * 4;
    int bb = l & 15;
#pragma unroll
    for (int i = 0; i < 4; i++) {
        int r = orow + i;
        ws[OFF_P + r * 16 + bb] = acc[i] + pb[r] + bc[r];   // 64B-contiguous per 16 lanes
    }
}

// ---- K3: Q'[b] = P[b] @ W_pre / 64 (bf16 out) + c' fold. grid 128 (b*8+mg), block 256 ----
__global__ __launch_bounds__(256) void k_q(const float* __restrict__ Wp, const float* __restrict__ bpre,
                                           float* __restrict__ ws) {
    int b = blockIdx.x >> 3, m0 = (blockIdx.x & 7) * 8, t = threadIdx.x;
    float acc0[8], acc1[8], cacc[8];
#pragma unroll
    for (int i = 0; i < 8; i++) { acc0[i] = 0.f; acc1[i] = 0.f; cacc[i] = 0.f; }
    const float* Pt = ws + OFF_P + b;      // P_t[r][16], batch offset folded
    for (int j = 0; j < 512; j++) {
        float w0 = Wp[j * 512 + t];
        float w1 = Wp[j * 512 + t + 256];
        float bpj = bpre[j];
#pragma unroll
        for (int mm = 0; mm < 8; mm++) {
            float p = Pt[((m0 + mm) * 512 + j) * 16];   // wave-uniform load
            acc0[mm] += p * w0;
            acc1[mm] += p * w1;
            cacc[mm] += p * bpj;
        }
    }
    unsigned short* Qb = (unsigned short*)(ws + OFF_QB);
#pragma unroll
    for (int mm = 0; mm < 8; mm++) {
        Qb[(b * 64 + m0 + mm) * 512 + t]       = f2bf(acc0[mm] * (1.0f / 64.0f));
        Qb[(b * 64 + m0 + mm) * 512 + t + 256] = f2bf(acc1[mm] * (1.0f / 64.0f));
    }
    if (t == 0) {
#pragma unroll
        for (int mm = 0; mm < 8; mm++)
            ws[OFF_CB + b * 64 + m0 + mm] = cacc[mm] * (1.0f / 64.0f);
    }
}

// ---- K4: logits = X.Q'^T + c' via bf16 MFMA + per-tile softmax partials. grid 1024, block 256 ----
__global__ __launch_bounds__(256) void k_logits(const float* __restrict__ X, float* __restrict__ ws) {
    int t = threadIdx.x;
    int W = blockIdx.x * 4 + (t >> 6);   // wave id 0..4095
    int b = W >> 8, nt = W & 255;        // batch, n-tile (16 rows)
    int l = t & 63, col = l & 15, kg = l >> 4;
    int nA = nt * 16 + col;              // A-fragment row
    const float4* X4 = (const float4*)X;
    const short8* Qb8 = (const short8*)(ws + OFF_QB);
    f32x4 acc[4];
#pragma unroll
    for (int mt = 0; mt < 4; mt++) acc[mt] = (f32x4){0.f, 0.f, 0.f, 0.f};

    int xbase4 = ((b * N_ + nA) * D_) >> 2;
    for (int kc = 0; kc < 16; kc++) {
        int k = kc * 32 + kg * 8;
        float4 xa = X4[xbase4 + (k >> 2)];
        float4 xb = X4[xbase4 + (k >> 2) + 1];
        short8 af;
        af[0] = (short)f2bf(xa.x); af[1] = (short)f2bf(xa.y);
        af[2] = (short)f2bf(xa.z); af[3] = (short)f2bf(xa.w);
        af[4] = (short)f2bf(xb.x); af[5] = (short)f2bf(xb.y);
        af[6] = (short)f2bf(xb.z); af[7] = (short)f2bf(xb.w);
#pragma unroll
        for (int mt = 0; mt < 4; mt++) {
            int m = mt * 16 + col;
            short8 bfr = Qb8[(b * 64 + m) * 64 + (k >> 3)];
            acc[mt] = __builtin_amdgcn_mfma_f32_16x16x32_bf16(af, bfr, acc[mt], 0, 0, 0);
        }
    }
    const float* cb = ws + OFF_CB + b * 64;
    float* LG = ws + OFF_LOGITS + b * (N_ * 64) + nt * 16 * 64;
#pragma unroll
    for (int mt = 0; mt < 4; mt++) {
        int m = mt * 16 + col;
        float c = cb[m];
        float v0 = acc[mt][0] + c, v1 = acc[mt][1] + c;
        float v2 = acc[mt][2] + c, v3 = acc[mt][3] + c;
        int nr = kg * 4;
        LG[(nr + 0) * 64 + m] = v0;
        LG[(nr + 1) * 64 + m] = v1;
        LG[(nr + 2) * 64 + m] = v2;
        LG[(nr + 3) * 64 + m] = v3;
        float mx = fmaxf(fmaxf(v0, v1), fmaxf(v2, v3));
        mx = fmaxf(mx, __shfl_xor(mx, 16));
        mx = fmaxf(mx, __shfl_xor(mx, 32));
        float s = expf(v0 - mx) + expf(v1 - mx) + expf(v2 - mx) + expf(v3 - mx);
        s += __shfl_xor(s, 16);
        s += __shfl_xor(s, 32);
        if (kg == 0) {
            ws[OFF_TPMAX + (b * 64 + m) * 256 + nt] = mx;
            ws[OFF_TPSUM + (b * 64 + m) * 256 + nt] = s;
        }
    }
}

// ---- K5: combine partials -> gmax, 1/denom. wave per (b,m). grid 256, block 256 ----
__global__ __launch_bounds__(256) void k_combine(float* __restrict__ ws) {
    int t = threadIdx.x;
    int w = blockIdx.x * 4 + (t >> 6);   // 0..1023 = b*64+m
    int l = t & 63;
    float4 a  = ((const float4*)(ws + OFF_TPMAX + w * 256))[l];
    float4 s4 = ((const float4*)(ws + OFF_TPSUM + w * 256))[l];
    float g = fmaxf(fmaxf(a.x, a.y), fmaxf(a.z, a.w));
    float s = s4.x * expf(a.x - g) + s4.y * expf(a.y - g)
            + s4.z * expf(a.z - g) + s4.w * expf(a.w - g);
#pragma unroll
    for (int off = 1; off < 64; off <<= 1) {
        float og = __shfl_xor(g, off);
        float os = __shfl_xor(s, off);
        float ng = fmaxf(g, og);
        s = s * expf(g - ng) + os * expf(og - ng);
        g = ng;
    }
    if (l == 0) { ws[OFF_GMAX + w] = g; ws[OFF_GINV + w] = 1.0f / s; }
}

// ---- K6: out = exp(l - gmax) * ginv. grid 4096, block 256 ----
__global__ __launch_bounds__(256) void k_final(const float* __restrict__ ws, float* __restrict__ out) {
    int idx = blockIdx.x * 256 + threadIdx.x;   // float4 index
    int flat = idx * 4;
    int b = flat >> 18;                         // / (4096*64)
    int m0 = flat & 63;                         // multiple of 4
    float4 l4 = ((const float4*)(ws + OFF_LOGITS))[idx];
    int bm = b * 64 + m0;
    float4 g4 = *(const float4*)(ws + OFF_GMAX + bm);
    float4 i4 = *(const float4*)(ws + OFF_GINV + bm);
    float4 o;
    o.x = expf(l4.x - g4.x) * i4.x;
    o.y = expf(l4.y - g4.y) * i4.y;
    o.z = expf(l4.z - g4.z) * i4.z;
    o.w = expf(l4.w - g4.w) * i4.w;
    ((float4*)out)[idx] = o;
}

extern "C" void kernel_launch(void* const* d_in, const int* in_sizes, int n_in,
                              void* d_out, int out_size, void* d_ws, size_t ws_size,
                              hipStream_t stream) {
    const float* X  = (const float*)d_in[0];
    const float* pb = (const float*)d_in[1];
    const float* Wc = (const float*)d_in[2];
    const float* bc = (const float*)d_in[3];
    const float* Wp = (const float*)d_in[4];
    const float* bp = (const float*)d_in[5];
    float* ws  = (float*)d_ws;
    float* out = (float*)d_out;

    k_pool<<<256, 256, 0, stream>>>(X, ws);
    k_ctx<<<64, 256, 0, stream>>>(ws);
    k_protos<<<512, 256, 0, stream>>>(Wc, pb, bc, ws);
    k_q<<<128, 256, 0, stream>>>(Wp, bp, ws);
    k_logits<<<1024, 256, 0, stream>>>(X, ws);
    k_combine<<<256, 256, 0, stream>>>(ws);
    k_final<<<4096, 256, 0, stream>>>(ws, out);
}

// Round 5
// 156.155 us; speedup vs baseline: 2.3626x; 1.6716x over previous
//
#include <hip/hip_runtime.h>
#include <math.h>

#define B_ 16
#define N_ 4096
#define D_ 512
#define M_ 64
#define MD 32768   // M_*D_

typedef __attribute__((ext_vector_type(4))) float f32x4;
typedef __attribute__((ext_vector_type(8))) short short8;

// ---- workspace layout (float offsets) ----
#define OFF_PSUM   0          // [16][16][512] pooling sum partials
#define OFF_PMAXP  131072     // [16][16][512] pooling max partials
#define OFF_CTXB   262144     // bf16 [16][1024] ctx (8192 floats worth)
#define OFF_P      270336     // fp32 P[b][m*512+d]  NATURAL layout (524288 floats)
#define OFF_CB     794624     // [16][64]  c' = (P . b_pre)/64
#define OFF_GMAX   795648     // [16][64]
#define OFF_GINV   796672     // [16][64]
#define OFF_TPMAX  797696     // [1024][256] per-ntile max   (bm-major)
#define OFF_TPSUM  1059840    // [1024][256] per-ntile sumexp
#define OFF_QB     1321984    // bf16 [16][64][512] = 524288 bf16 = 262144 floats
#define OFF_LOGITS 1584128    // [16][4096][64]
// total = 5778432 floats = 23.1 MB

__device__ __forceinline__ unsigned short f2bf(float f) {
    unsigned int u = __float_as_uint(f);
    u += 0x7fffu + ((u >> 16) & 1u);   // round-to-nearest-even
    return (unsigned short)(u >> 16);
}

// ---- K1: pooling partials. grid 256 (b*16+nc), block 256 ----
__global__ __launch_bounds__(256) void k_pool(const float* __restrict__ X, float* __restrict__ ws) {
    int b = blockIdx.x >> 4, nc = blockIdx.x & 15, t = threadIdx.x;
    const float2* X2 = (const float2*)X;
    float2 s = make_float2(0.f, 0.f);
    float2 mx = make_float2(-INFINITY, -INFINITY);
    int base = (b * N_ + nc * 256) * 256 + t;   // float2 units; row stride 256
    for (int n = 0; n < 256; n++) {
        float2 v = X2[base + n * 256];
        s.x += v.x; s.y += v.y;
        mx.x = fmaxf(mx.x, v.x); mx.y = fmaxf(mx.y, v.y);
    }
    ((float2*)(ws + OFF_PSUM))[blockIdx.x * 256 + t] = s;
    ((float2*)(ws + OFF_PMAXP))[blockIdx.x * 256 + t] = mx;
}

// ---- K1b: finalize ctx -> bf16 [b][1024]. grid 64, block 256 ----
__global__ __launch_bounds__(256) void k_ctx(float* __restrict__ ws) {
    int idx = blockIdx.x * 256 + threadIdx.x;     // 0..16383 = b*1024 + k
    int b = idx >> 10, k = idx & 1023;
    float v;
    if (k < 512) {
        float s = 0.f;
        for (int c = 0; c < 16; c++) s += ws[OFF_PSUM + (b * 16 + c) * 512 + k];
        v = s * (1.0f / 4096.0f);
    } else {
        int d = k - 512;
        float m = -INFINITY;
        for (int c = 0; c < 16; c++) m = fmaxf(m, ws[OFF_PMAXP + (b * 16 + c) * 512 + d]);
        v = m;
    }
    ((unsigned short*)(ws + OFF_CTXB))[idx] = f2bf(v);
}

// ---- K2: P via MFMA: A=ctx[16b x K], B=W rows -> C[b][r]. grid 512, block 256 ----
// Same fragment loads as before; operands swapped so output rows = batches ->
// natural P[b][r] layout with 64B-contiguous stores.
__global__ __launch_bounds__(256) void k_protos(const float* __restrict__ Wc, const float* __restrict__ pb,
                                                const float* __restrict__ bc, float* __restrict__ ws) {
    int t = threadIdx.x;
    int wave = blockIdx.x * 4 + (t >> 6);   // 0..2047 tiles of 16 W-rows
    int l = t & 63;
    int r0 = wave * 16;
    int row = r0 + (l & 15);                // this lane's W-row (B-frag col)
    int kg = l >> 4;
    const float4* W4 = (const float4*)Wc;                  // row stride 256 float4
    const short8* CB8 = (const short8*)(ws + OFF_CTXB);    // [16][128] short8 units
    f32x4 acc = (f32x4){0.f, 0.f, 0.f, 0.f};
    int wb = row * 256 + kg * 2;            // float4 idx: k = kg*8
    int cbase = (l & 15) * 128 + kg;        // A-frag: lane&15 = batch row
#pragma unroll 4
    for (int kc = 0; kc < 32; kc++) {
        float4 xa = W4[wb + kc * 8];
        float4 xb = W4[wb + kc * 8 + 1];
        short8 wf;
        wf[0] = (short)f2bf(xa.x); wf[1] = (short)f2bf(xa.y);
        wf[2] = (short)f2bf(xa.z); wf[3] = (short)f2bf(xa.w);
        wf[4] = (short)f2bf(xb.x); wf[5] = (short)f2bf(xb.y);
        wf[6] = (short)f2bf(xb.z); wf[7] = (short)f2bf(xb.w);
        short8 cf = CB8[cbase + kc * 4];
        acc = __builtin_amdgcn_mfma_f32_16x16x32_bf16(cf, wf, acc, 0, 0, 0);  // A=ctx, B=W
    }
    // D: col = l&15 -> r = r0+(l&15); row = kg*4+i -> batch
    int r = r0 + (l & 15);
    float add = pb[r] + bc[r];
#pragma unroll
    for (int i = 0; i < 4; i++) {
        int bb = kg * 4 + i;
        ws[OFF_P + bb * MD + r] = acc[i] + add;   // 16 lanes -> 64B contiguous
    }
}

// ---- K3: Q'[b] = P[b] @ W_pre / 64 (bf16 out), fp32 math, LDS-staged P. ----
// grid 512 = b(16) x mg(16) x ch(2); block 256. Block: 4 m-rows, 256 cols.
__global__ __launch_bounds__(256) void k_q(const float* __restrict__ Wp, float* __restrict__ ws) {
    __shared__ float4 lds4[512];            // [mm][128] float4 = P rows m0..m0+3
    int bx = blockIdx.x;
    int b = bx >> 5, mg = (bx >> 1) & 15, ch = bx & 1;
    int m0 = mg * 4, t = threadIdx.x;
    const float4* P4 = (const float4*)(ws + OFF_P + b * MD + m0 * 512);
    lds4[t] = P4[t];
    lds4[t + 256] = P4[t + 256];
    __syncthreads();
    int col = ch * 256 + t;
    const float* W = Wp + col;
    float acc0 = 0.f, acc1 = 0.f, acc2 = 0.f, acc3 = 0.f;
#pragma unroll 4
    for (int j4 = 0; j4 < 128; j4++) {
        float4 p0 = lds4[j4];
        float4 p1 = lds4[128 + j4];
        float4 p2 = lds4[256 + j4];
        float4 p3 = lds4[384 + j4];
        float w0 = W[(4 * j4 + 0) * 512];
        float w1 = W[(4 * j4 + 1) * 512];
        float w2 = W[(4 * j4 + 2) * 512];
        float w3 = W[(4 * j4 + 3) * 512];
        acc0 += p0.x * w0 + p0.y * w1 + p0.z * w2 + p0.w * w3;
        acc1 += p1.x * w0 + p1.y * w1 + p1.z * w2 + p1.w * w3;
        acc2 += p2.x * w0 + p2.y * w1 + p2.z * w2 + p2.w * w3;
        acc3 += p3.x * w0 + p3.y * w1 + p3.z * w2 + p3.w * w3;
    }
    unsigned short* Qb = (unsigned short*)(ws + OFF_QB);
    int qb = (b * 64 + m0) * 512 + col;
    Qb[qb]            = f2bf(acc0 * (1.0f / 64.0f));
    Qb[qb + 512]      = f2bf(acc1 * (1.0f / 64.0f));
    Qb[qb + 1024]     = f2bf(acc2 * (1.0f / 64.0f));
    Qb[qb + 1536]     = f2bf(acc3 * (1.0f / 64.0f));
}

// ---- K3b: c'[b][m] = (P[b][m] . b_pre)/64. wave per (b,m). grid 256, block 256 ----
__global__ __launch_bounds__(256) void k_cb(const float* __restrict__ bpre, float* __restrict__ ws) {
    int t = threadIdx.x;
    int w = blockIdx.x * 4 + (t >> 6);   // 0..1023 = b*64+m
    int l = t & 63;
    int b = w >> 6, m = w & 63;
    const float4* P4 = (const float4*)(ws + OFF_P + b * MD + m * 512);
    const float4* bp4 = (const float4*)bpre;
    float4 p0 = P4[l * 2],     q0 = bp4[l * 2];
    float4 p1 = P4[l * 2 + 1], q1 = bp4[l * 2 + 1];
    float s = p0.x * q0.x + p0.y * q0.y + p0.z * q0.z + p0.w * q0.w
            + p1.x * q1.x + p1.y * q1.y + p1.z * q1.z + p1.w * q1.w;
#pragma unroll
    for (int off = 1; off < 64; off <<= 1) s += __shfl_xor(s, off);
    if (l == 0) ws[OFF_CB + w] = s * (1.0f / 64.0f);
}

// ---- K4: logits = X.Q'^T + c' via bf16 MFMA + per-tile softmax partials. grid 1024, block 256 ----
__global__ __launch_bounds__(256) void k_logits(const float* __restrict__ X, float* __restrict__ ws) {
    int t = threadIdx.x;
    int W = blockIdx.x * 4 + (t >> 6);   // wave id 0..4095
    int b = W >> 8, nt = W & 255;        // batch, n-tile (16 rows)
    int l = t & 63, col = l & 15, kg = l >> 4;
    int nA = nt * 16 + col;              // A-fragment row
    const float4* X4 = (const float4*)X;
    const short8* Qb8 = (const short8*)(ws + OFF_QB);
    f32x4 acc[4];
#pragma unroll
    for (int mt = 0; mt < 4; mt++) acc[mt] = (f32x4){0.f, 0.f, 0.f, 0.f};

    int xbase4 = ((b * N_ + nA) * D_) >> 2;
    for (int kc = 0; kc < 16; kc++) {
        int k = kc * 32 + kg * 8;
        float4 xa = X4[xbase4 + (k >> 2)];
        float4 xb = X4[xbase4 + (k >> 2) + 1];
        short8 af;
        af[0] = (short)f2bf(xa.x); af[1] = (short)f2bf(xa.y);
        af[2] = (short)f2bf(xa.z); af[3] = (short)f2bf(xa.w);
        af[4] = (short)f2bf(xb.x); af[5] = (short)f2bf(xb.y);
        af[6] = (short)f2bf(xb.z); af[7] = (short)f2bf(xb.w);
#pragma unroll
        for (int mt = 0; mt < 4; mt++) {
            int m = mt * 16 + col;
            short8 bfr = Qb8[(b * 64 + m) * 64 + (k >> 3)];
            acc[mt] = __builtin_amdgcn_mfma_f32_16x16x32_bf16(af, bfr, acc[mt], 0, 0, 0);
        }
    }
    const float* cb = ws + OFF_CB + b * 64;
    float* LG = ws + OFF_LOGITS + b * (N_ * 64) + nt * 16 * 64;
#pragma unroll
    for (int mt = 0; mt < 4; mt++) {
        int m = mt * 16 + col;
        float c = cb[m];
        float v0 = acc[mt][0] + c, v1 = acc[mt][1] + c;
        float v2 = acc[mt][2] + c, v3 = acc[mt][3] + c;
        int nr = kg * 4;
        LG[(nr + 0) * 64 + m] = v0;
        LG[(nr + 1) * 64 + m] = v1;
        LG[(nr + 2) * 64 + m] = v2;
        LG[(nr + 3) * 64 + m] = v3;
        float mx = fmaxf(fmaxf(v0, v1), fmaxf(v2, v3));
        mx = fmaxf(mx, __shfl_xor(mx, 16));
        mx = fmaxf(mx, __shfl_xor(mx, 32));
        float s = expf(v0 - mx) + expf(v1 - mx) + expf(v2 - mx) + expf(v3 - mx);
        s += __shfl_xor(s, 16);
        s += __shfl_xor(s, 32);
        if (kg == 0) {
            ws[OFF_TPMAX + (b * 64 + m) * 256 + nt] = mx;
            ws[OFF_TPSUM + (b * 64 + m) * 256 + nt] = s;
        }
    }
}

// ---- K5: combine partials -> gmax, 1/denom. wave per (b,m). grid 256, block 256 ----
__global__ __launch_bounds__(256) void k_combine(float* __restrict__ ws) {
    int t = threadIdx.x;
    int w = blockIdx.x * 4 + (t >> 6);   // 0..1023 = b*64+m
    int l = t & 63;
    float4 a  = ((const float4*)(ws + OFF_TPMAX + w * 256))[l];
    float4 s4 = ((const float4*)(ws + OFF_TPSUM + w * 256))[l];
    float g = fmaxf(fmaxf(a.x, a.y), fmaxf(a.z, a.w));
    float s = s4.x * expf(a.x - g) + s4.y * expf(a.y - g)
            + s4.z * expf(a.z - g) + s4.w * expf(a.w - g);
#pragma unroll
    for (int off = 1; off < 64; off <<= 1) {
        float og = __shfl_xor(g, off);
        float os = __shfl_xor(s, off);
        float ng = fmaxf(g, og);
        s = s * expf(g - ng) + os * expf(og - ng);
        g = ng;
    }
    if (l == 0) { ws[OFF_GMAX + w] = g; ws[OFF_GINV + w] = 1.0f / s; }
}

// ---- K6: out = exp(l - gmax) * ginv. grid 4096, block 256 ----
__global__ __launch_bounds__(256) void k_final(const float* __restrict__ ws, float* __restrict__ out) {
    int idx = blockIdx.x * 256 + threadIdx.x;   // float4 index
    int flat = idx * 4;
    int b = flat >> 18;                         // / (4096*64)
    int m0 = flat & 63;                         // multiple of 4
    float4 l4 = ((const float4*)(ws + OFF_LOGITS))[idx];
    int bm = b * 64 + m0;
    float4 g4 = *(const float4*)(ws + OFF_GMAX + bm);
    float4 i4 = *(const float4*)(ws + OFF_GINV + bm);
    float4 o;
    o.x = expf(l4.x - g4.x) * i4.x;
    o.y = expf(l4.y - g4.y) * i4.y;
    o.z = expf(l4.z - g4.z) * i4.z;
    o.w = expf(l4.w - g4.w) * i4.w;
    ((float4*)out)[idx] = o;
}

extern "C" void kernel_launch(void* const* d_in, const int* in_sizes, int n_in,
                              void* d_out, int out_size, void* d_ws, size_t ws_size,
                              hipStream_t stream) {
    const float* X  = (const float*)d_in[0];
    const float* pb = (const float*)d_in[1];
    const float* Wc = (const float*)d_in[2];
    const float* bc = (const float*)d_in[3];
    const float* Wp = (const float*)d_in[4];
    const float* bp = (const float*)d_in[5];
    float* ws  = (float*)d_ws;
    float* out = (float*)d_out;

    k_pool<<<256, 256, 0, stream>>>(X, ws);
    k_ctx<<<64, 256, 0, stream>>>(ws);
    k_protos<<<512, 256, 0, stream>>>(Wc, pb, bc, ws);
    k_q<<<512, 256, 0, stream>>>(Wp, ws);
    k_cb<<<256, 256, 0, stream>>>(bp, ws);
    k_logits<<<1024, 256, 0, stream>>>(X, ws);
    k_combine<<<256, 256, 0, stream>>>(ws);
    k_final<<<4096, 256, 0, stream>>>(ws, out);
}